// Round 2
// baseline (15265.086 us; speedup 1.0000x reference)
//
#include <hip/hip_runtime.h>
#include <utility>

// SO(3) bispectrum: out[b,t] = sum_{m1,m2,m} cg[t,m1,m2,m] * x[b,l1^2+m1] * x[b,l2^2+m2] * x[b,l^2+m]
// LMAX=8, NCOEF=81, 215 triples, cg stored dense (215,17,17,17) with RANDOM (not zero) padding.

#define LMAXV 8
#define NCOEFV 81
#define NTRI 215
#define CGSTRIDE (17 * 17 * 17)

struct Tri { int l1, l2, l3; };
struct TriTab { Tri a[NTRI]; int n; };

constexpr TriTab make_tab() {
    TriTab t{};
    int n = 0;
    for (int l1 = 0; l1 <= LMAXV; ++l1)
        for (int l2 = l1; l2 <= LMAXV; ++l2) {
            int lo = l1 + l2 < LMAXV ? l1 + l2 : LMAXV;
            for (int l = l2 - l1; l <= lo; ++l) {
                t.a[n] = Tri{l1, l2, l};
                ++n;
            }
        }
    t.n = n;
    return t;
}
constexpr TriTab TAB = make_tab();
static_assert(TAB.n == NTRI, "triple count mismatch");

// One triple, compile-time (L1,L2,L3). xrow = this thread's 81 coeffs in LDS
// (dynamic index OK there). F3 block lives in registers with static indexing
// only. C accesses are wave-uniform -> scalar loads feeding v_fma_f32.
template <int L1, int L2, int L3>
__device__ __forceinline__ float do_triple(const float* xrow, const float* __restrict__ C) {
    constexpr int D1 = 2 * L1 + 1, D2 = 2 * L2 + 1, D3 = 2 * L3 + 1;
    float F3[D3];
#pragma unroll
    for (int m = 0; m < D3; ++m) F3[m] = xrow[L3 * L3 + m];
    float acc = 0.f;
#pragma unroll 1
    for (int m1 = 0; m1 < D1; ++m1) {
        float f1 = xrow[L1 * L1 + m1];
#pragma unroll 1
        for (int m2 = 0; m2 < D2; ++m2) {
            float p = f1 * xrow[L2 * L2 + m2];
            const float* Crow = C + (m1 * 17 + m2) * 17;
            // D3 is always odd; even/odd split -> 2 independent FMA chains
            float s0 = 0.f, s1 = 0.f;
#pragma unroll
            for (int m = 0; m + 1 < D3; m += 2) {
                s0 += Crow[m] * F3[m];
                s1 += Crow[m + 1] * F3[m + 1];
            }
            s0 += Crow[D3 - 1] * F3[D3 - 1];
            acc += p * (s0 + s1);
        }
    }
    return acc;
}

template <int T>
__device__ __forceinline__ void run_one(const float* xrow, const float* __restrict__ cg,
                                        float* __restrict__ outrow) {
    constexpr Tri tr = TAB.a[T];
    outrow[T] = do_triple<tr.l1, tr.l2, tr.l3>(xrow, cg + (long)T * CGSTRIDE);
}

template <int... I>
__device__ __forceinline__ void run_all(std::integer_sequence<int, I...>, const float* xrow,
                                        const float* __restrict__ cg, float* __restrict__ outrow) {
    (run_one<I>(xrow, cg, outrow), ...);
}

__global__ __launch_bounds__(64) void SO3onS2_58420145160629_kernel(
    const float* __restrict__ x, const float* __restrict__ cg, float* __restrict__ out) {
    __shared__ float xs[64 * NCOEFV];
    const int tid = threadIdx.x;
    const long b0 = (long)blockIdx.x * 64;

    // coalesced cooperative load of 64 rows x 81 coeffs into LDS
    for (int k = tid; k < 64 * NCOEFV; k += 64) xs[k] = x[b0 * NCOEFV + k];
    __syncthreads();

    const float* xrow = xs + tid * NCOEFV;  // stride 81 (odd) -> bank-conflict-free
    float* outrow = out + (b0 + tid) * NTRI;
    run_all(std::make_integer_sequence<int, NTRI>{}, xrow, cg, outrow);
}

extern "C" void kernel_launch(void* const* d_in, const int* in_sizes, int n_in,
                              void* d_out, int out_size, void* d_ws, size_t ws_size,
                              hipStream_t stream) {
    const float* x = (const float*)d_in[0];
    const float* cg = (const float*)d_in[1];
    float* out = (float*)d_out;
    const int B = in_sizes[0] / NCOEFV;  // 131072
    SO3onS2_58420145160629_kernel<<<dim3(B / 64), dim3(64), 0, stream>>>(x, cg, out);
}

// Round 4
// 4271.189 us; speedup vs baseline: 3.5740x; 3.5740x over previous
//
#include <hip/hip_runtime.h>
#include <utility>

// SO(3) bispectrum: out[b,t] = sum_{m1,m2,m} cg[t,m1,m2,m] * x[b,l1^2+m1] * x[b,l2^2+m2] * x[b,l^2+m]
// LMAX=8, NCOEF=81, 215 triples, cg stored dense (215,17,17,17).
// R2: 4 waves/block share one 64-row LDS tile; triples cost-partitioned across waves.

#define LMAXV 8
#define NCOEFV 81
#define NTRI 215
#define CGSTRIDE (17 * 17 * 17)

struct Tri { int l1, l2, l3; };
struct TriTab { Tri a[NTRI]; int n; };

constexpr TriTab make_tab() {
    TriTab t{};
    int n = 0;
    for (int l1 = 0; l1 <= LMAXV; ++l1)
        for (int l2 = l1; l2 <= LMAXV; ++l2) {
            int lo = l1 + l2 < LMAXV ? l1 + l2 : LMAXV;
            for (int l = l2 - l1; l <= lo; ++l) {
                t.a[n] = Tri{l1, l2, l};
                ++n;
            }
        }
    t.n = n;
    return t;
}
constexpr TriTab TAB = make_tab();
static_assert(TAB.n == NTRI, "triple count mismatch");

constexpr int tri_cost(int t) {
    return (2 * TAB.a[t].l1 + 1) * (2 * TAB.a[t].l2 + 1) * (2 * TAB.a[t].l3 + 1);
}

// Cost-balanced contiguous 4-way partition of the triple list.
struct Part { int b[5]; };
constexpr Part make_part() {
    Part p{};
    int total = 0;
    for (int t = 0; t < NTRI; ++t) total += tri_cost(t);
    p.b[0] = 0; p.b[4] = NTRI;
    int acc = 0, idx = 1;
    for (int t = 0; t < NTRI && idx < 4; ++t) {
        acc += tri_cost(t);
        if (acc * 4 >= total * idx) { p.b[idx] = t + 1; ++idx; }
    }
    return p;
}
constexpr Part PART = make_part();

// One triple, compile-time (L1,L2,L3). xrow = this lane's 81 coeffs in LDS
// (dynamic index OK there). F3 block lives in registers, static indexing only.
// C accesses are wave-uniform -> scalar loads feeding v_fma_f32.
template <int L1, int L2, int L3>
__device__ __forceinline__ float do_triple(const float* xrow, const float* __restrict__ C) {
    constexpr int D1 = 2 * L1 + 1, D2 = 2 * L2 + 1, D3 = 2 * L3 + 1;
    float F3[D3];
#pragma unroll
    for (int m = 0; m < D3; ++m) F3[m] = xrow[L3 * L3 + m];
    float acc = 0.f;
#pragma unroll 1
    for (int m1 = 0; m1 < D1; ++m1) {
        float f1 = xrow[L1 * L1 + m1];
#pragma unroll 2
        for (int m2 = 0; m2 < D2; ++m2) {
            float p = f1 * xrow[L2 * L2 + m2];
            const float* Crow = C + (m1 * 17 + m2) * 17;
            // D3 is always odd; even/odd split -> 2 independent FMA chains
            float s0 = 0.f, s1 = 0.f;
#pragma unroll
            for (int m = 0; m + 1 < D3; m += 2) {
                s0 += Crow[m] * F3[m];
                s1 += Crow[m + 1] * F3[m + 1];
            }
            s0 += Crow[D3 - 1] * F3[D3 - 1];
            acc += p * (s0 + s1);
        }
    }
    return acc;
}

template <int T>
__device__ __forceinline__ void run_one(const float* xrow, const float* __restrict__ cg,
                                        float* __restrict__ outrow) {
    constexpr Tri tr = TAB.a[T];
    outrow[T] = do_triple<tr.l1, tr.l2, tr.l3>(xrow, cg + (long)T * CGSTRIDE);
}

template <int Lo, int... I>
__device__ __forceinline__ void run_range_impl(std::integer_sequence<int, I...>,
                                               const float* xrow, const float* __restrict__ cg,
                                               float* __restrict__ outrow) {
    (run_one<Lo + I>(xrow, cg, outrow), ...);
}

template <int Lo, int Hi>
__device__ __forceinline__ void run_range(const float* xrow, const float* __restrict__ cg,
                                          float* __restrict__ outrow) {
    run_range_impl<Lo>(std::make_integer_sequence<int, Hi - Lo>{}, xrow, cg, outrow);
}

__global__ __launch_bounds__(256) void SO3onS2_58420145160629_kernel(
    const float* __restrict__ x, const float* __restrict__ cg, float* __restrict__ out) {
    __shared__ float xs[64 * NCOEFV];
    const int tid = threadIdx.x;
    const int lane = tid & 63;
    const int wave = tid >> 6;
    const long b0 = (long)blockIdx.x * 64;

    // coalesced cooperative load of 64 rows x 81 coeffs into LDS
    for (int k = tid; k < 64 * NCOEFV; k += 256) xs[k] = x[b0 * NCOEFV + k];
    __syncthreads();

    const float* xrow = xs + lane * NCOEFV;  // stride 81 (odd) -> bank-conflict-free
    float* outrow = out + (b0 + lane) * NTRI;

    // each wave runs its cost-balanced chunk of the 215 triples
    if (wave == 0)      run_range<PART.b[0], PART.b[1]>(xrow, cg, outrow);
    else if (wave == 1) run_range<PART.b[1], PART.b[2]>(xrow, cg, outrow);
    else if (wave == 2) run_range<PART.b[2], PART.b[3]>(xrow, cg, outrow);
    else                run_range<PART.b[3], PART.b[4]>(xrow, cg, outrow);
}

extern "C" void kernel_launch(void* const* d_in, const int* in_sizes, int n_in,
                              void* d_out, int out_size, void* d_ws, size_t ws_size,
                              hipStream_t stream) {
    const float* x = (const float*)d_in[0];
    const float* cg = (const float*)d_in[1];
    float* out = (float*)d_out;
    const int B = in_sizes[0] / NCOEFV;  // 131072
    SO3onS2_58420145160629_kernel<<<dim3(B / 64), dim3(256), 0, stream>>>(x, cg, out);
}

// Round 5
// 1005.908 us; speedup vs baseline: 15.1754x; 4.2461x over previous
//
#include <hip/hip_runtime.h>
#include <utility>

// SO(3) bispectrum via per-(l1,l2)-pair bf16 MFMA GEMMs.
// out[b,t] = sum_{m1,m2,m} cg[t,m1,m2,m] * F1[b,m1] * F2[b,m2] * F3[b,m]
// Reformulated: G[b,(m1,m2)] = F1*F2 (bf16, LDS, XOR-swizzled)
//               P[b,n] = G . Cp   (MFMA 16x16x32, fp32 acc; Cp = packed bf16 cg in d_ws)
//               out[b,t] = sum_m P[b,off_t+m] * F3[b,m]  (fp32 epilogue in LDS)

#define LMAXV 8
#define NCOEFV 81
#define NTRIV 215
#define CGS 4913          // 17*17*17
#define NPAIRS 45
#define THREADS 512
#define PSTR 96           // fp32 row stride of P tile (max N=81 -> 96)

typedef float f32x4 __attribute__((ext_vector_type(4)));
typedef __bf16 bf16x8 __attribute__((ext_vector_type(8)));

struct PairInfo {
    int l1, l2, D1, D2, K, Kpad, KS, lmin, nl, N, NT, tstart, cpbase;
};
struct PairTab { PairInfo p[NPAIRS]; int nft; int cptot; };

constexpr PairTab make_pairs() {
    PairTab tb{};
    int idx = 0, t = 0, cpb = 0, ft = 0;
    for (int l1 = 0; l1 <= LMAXV; ++l1)
        for (int l2 = l1; l2 <= LMAXV; ++l2) {
            PairInfo pi{};
            pi.l1 = l1; pi.l2 = l2;
            pi.D1 = 2 * l1 + 1; pi.D2 = 2 * l2 + 1;
            pi.K = pi.D1 * pi.D2;
            pi.Kpad = (pi.K + 31) & ~31;
            pi.KS = pi.Kpad / 32;
            pi.lmin = l2 - l1;
            int lmax = (l1 + l2 < LMAXV) ? (l1 + l2) : LMAXV;
            pi.nl = lmax - pi.lmin + 1;
            int N = 0;
            for (int l = pi.lmin; l <= lmax; ++l) N += 2 * l + 1;
            pi.N = N;
            pi.NT = (N + 15) / 16;
            pi.tstart = t;
            t += pi.nl;
            pi.cpbase = cpb;
            cpb += pi.NT * pi.KS * 512;   // elements (bf16)
            ft += pi.NT * pi.KS;
            tb.p[idx++] = pi;
        }
    tb.nft = ft; tb.cptot = cpb;
    return tb;
}
constexpr PairTab PT = make_pairs();
__device__ const PairTab d_PT = make_pairs();   // runtime-indexable copy for prep

static_assert(PT.p[NPAIRS - 1].tstart + PT.p[NPAIRS - 1].nl == NTRIV, "triple count");
static_assert(PT.p[NPAIRS - 1].Kpad == 320, "max Kpad");

__device__ __forceinline__ unsigned short f2bf(float f) {   // RNE f32 -> bf16 bits
    unsigned u = __float_as_uint(f);
    return (unsigned short)((u + 0x7fffu + ((u >> 16) & 1u)) >> 16);
}

// ---- prep: pack cg (fp32) into fragment-linear bf16 Cp in d_ws, zero-padded.
// One 64-thread block per (pair, nt, ks) fragment tile. Lane l holds
// B[k = ks*32 + (l>>4)*8 + i][n = nt*16 + (l&15)], 8 bf16 = 16B, stored linearly.
__global__ __launch_bounds__(64) void prep_kernel(const float* __restrict__ cg,
                                                  unsigned short* __restrict__ cp) {
    int bid = blockIdx.x, lane = threadIdx.x;
    int p = 0, base = 0;
    while (p < NPAIRS - 1 && bid >= base + d_PT.p[p].NT * d_PT.p[p].KS) {
        base += d_PT.p[p].NT * d_PT.p[p].KS; ++p;
    }
    PairInfo pi = d_PT.p[p];
    int local = bid - base;
    int nt = local / pi.KS, ks = local - nt * pi.KS;
    int n = nt * 16 + (lane & 15);
    int kb = ks * 32 + (lane >> 4) * 8;
    int tl = -1, m = 0;
    if (n < pi.N) {
        int off = 0;
        for (int q = 0; q < pi.nl; ++q) {
            int D3 = 2 * (pi.lmin + q) + 1;
            if (n < off + D3) { tl = q; m = n - off; break; }
            off += D3;
        }
    }
    unsigned short vals[8];
#pragma unroll
    for (int i = 0; i < 8; ++i) {
        int k = kb + i;
        float v = 0.f;
        if (tl >= 0 && k < pi.K) {
            int m1 = k / pi.D2, m2 = k - (k / pi.D2) * pi.D2;
            v = cg[(long)(pi.tstart + tl) * CGS + (m1 * 17 + m2) * 17 + m];
        }
        vals[i] = f2bf(v);
    }
    *reinterpret_cast<bf16x8*>(cp + pi.cpbase + ((long)(nt * pi.KS + ks) * 64 + lane) * 8) =
        *reinterpret_cast<bf16x8*>(vals);
}

// ---- per-pair step inside the main kernel (all shapes compile-time)
template <int P>
__device__ __forceinline__ void pair_step(float* xs, unsigned short* gs, float* outl,
                                          const unsigned short* __restrict__ cp,
                                          int wave, int lane) {
    constexpr PairInfo pi = PT.p[P];
    constexpr int D1 = pi.D1, D2 = pi.D2, K = pi.K, Kpad = pi.Kpad, KS = pi.KS, NT = pi.NT;
    constexpr int SWM = ((Kpad / 8) < 8 ? (Kpad / 8) : 8) - 1;  // XOR-swizzle row mask
    const int tid = wave * 64 + lane;

    __syncthreads();  // (1) prev pair's P reads done -> G region writable
    // ---- G build: G[row][j=(m1,m2)] = F1[row][m1]*F2[row][m2], bf16, swizzled
    {
        constexpr int TASKS = 64 * D1;
        for (int task = tid; task < TASKS; task += THREADS) {
            const int row = task / D1;
            const int m1 = task - (task / D1) * D1;
            const float f1 = xs[row * NCOEFV + pi.l1 * pi.l1 + m1];
            const float* f2p = xs + row * NCOEFV + pi.l2 * pi.l2;
            const unsigned rowb = (unsigned)row * (Kpad * 2);
            const unsigned swz = ((unsigned)row & SWM) << 4;
            const int jb = m1 * D2;
#pragma unroll
            for (int m2 = 0; m2 < D2; ++m2) {
                unsigned short b = f2bf(f1 * f2p[m2]);
                *(unsigned short*)((char*)gs + ((rowb + (unsigned)(jb + m2) * 2) ^ swz)) = b;
            }
        }
        constexpr int PAD = Kpad - K;
        if constexpr (PAD > 0) {   // zero k-padding (avoid NaN garbage * 0)
            for (int task = tid; task < 64 * PAD; task += THREADS) {
                const int row = task / PAD;
                const int j = K + (task - (task / PAD) * PAD);
                const unsigned swz = ((unsigned)row & SWM) << 4;
                *(unsigned short*)((char*)gs +
                    (((unsigned)row * (Kpad * 2) + (unsigned)j * 2) ^ swz)) = 0;
            }
        }
    }
    __syncthreads();  // (2) G ready
    // ---- hoist A-frags for this wave's 16-row slice into registers
    const int slice = wave >> 1, cidx = wave & 1;
    bf16x8 af[KS];
    {
        const int row = slice * 16 + (lane & 15);
        const unsigned rowb = (unsigned)row * (Kpad * 2);
        const unsigned swz = ((unsigned)row & SWM) << 4;
        const unsigned kb = ((unsigned)(lane >> 4)) * 16;
#pragma unroll
        for (int ks = 0; ks < KS; ++ks)
            af[ks] = *(const bf16x8*)((const char*)gs + ((rowb + ks * 64 + kb) ^ swz));
    }
    __syncthreads();  // (3) all waves hoisted -> G region reused as P tile
    float* Pl = (float*)gs;   // P[64][PSTR] fp32
    const bf16x8* cpf = (const bf16x8*)(cp + pi.cpbase);
#pragma unroll
    for (int nt = 0; nt < NT; ++nt) {
        if ((nt & 1) != cidx) continue;   // 2-way col split across wave groups
        f32x4 acc = {0.f, 0.f, 0.f, 0.f};
#pragma unroll
        for (int ks = 0; ks < KS; ++ks) {
            bf16x8 bf = cpf[(nt * KS + ks) * 64 + lane];   // coalesced, L1/L2-hot
            acc = __builtin_amdgcn_mfma_f32_16x16x32_bf16(af[ks], bf, acc, 0, 0, 0);
        }
        const int col = lane & 15;
        const int row0 = slice * 16 + ((lane >> 4) << 2);  // C/D: col=lane&15, row=(lane>>4)*4+r
#pragma unroll
        for (int r = 0; r < 4; ++r)
            Pl[(row0 + r) * PSTR + nt * 16 + col] = acc[r];
    }
    __syncthreads();  // (4) P complete
    // ---- epilogue: out[row][tstart+tl] = sum_m P[row][noff+m] * F3[row][m]
    {
        constexpr int NL = pi.nl, LMIN = pi.lmin, TSTART = pi.tstart;
        for (int task = tid; task < 64 * NL; task += THREADS) {
            const int row = task / NL;
            const int tl = task - (task / NL) * NL;
            const int l = LMIN + tl;
            const int D3 = 2 * l + 1;
            const int noff = tl * (2 * LMIN + tl);   // sum of prior D3s
            const float* Pr = Pl + row * PSTR + noff;
            const float* f3 = xs + row * NCOEFV + l * l;
            float s = 0.f;
            for (int m = 0; m < D3; ++m) s += Pr[m] * f3[m];
            outl[row * NTRIV + TSTART + tl] = s;
        }
    }
}

template <int... I>
__device__ __forceinline__ void run_pairs(std::integer_sequence<int, I...>, float* xs,
                                          unsigned short* gs, float* outl,
                                          const unsigned short* __restrict__ cp,
                                          int wave, int lane) {
    (pair_step<I>(xs, gs, outl, cp, wave, lane), ...);
}

__global__ __launch_bounds__(THREADS) void SO3onS2_58420145160629_kernel(
    const float* __restrict__ x, const unsigned short* __restrict__ cp,
    float* __restrict__ out) {
    __shared__ float xs[64 * NCOEFV];            // 20736 B  (fp32 x-tile, 64 rows)
    __shared__ unsigned short gs[64 * 320];      // 40960 B  (G bf16 / P fp32, reused)
    __shared__ float outl[64 * NTRIV];           // 55040 B  (fp32 out-tile)
    const int tid = threadIdx.x;
    const int lane = tid & 63, wave = tid >> 6;
    const long b0 = (long)blockIdx.x * 64;

    for (int i = tid; i < 64 * NCOEFV; i += THREADS) xs[i] = x[b0 * NCOEFV + i];
    // pair_step starts with __syncthreads -> covers the x-tile load
    run_pairs(std::make_integer_sequence<int, NPAIRS>{}, xs, gs, outl, cp, wave, lane);
    __syncthreads();
    float* og = out + b0 * NTRIV;
    for (int i = tid; i < 64 * NTRIV; i += THREADS) og[i] = outl[i];   // coalesced
}

extern "C" void kernel_launch(void* const* d_in, const int* in_sizes, int n_in,
                              void* d_out, int out_size, void* d_ws, size_t ws_size,
                              hipStream_t stream) {
    const float* x = (const float*)d_in[0];
    const float* cg = (const float*)d_in[1];
    float* out = (float*)d_out;
    unsigned short* cp = (unsigned short*)d_ws;   // PT.cptot bf16 elements (~640 KB)
    const int B = in_sizes[0] / NCOEFV;           // 131072
    prep_kernel<<<dim3(PT.nft), dim3(64), 0, stream>>>(cg, cp);
    SO3onS2_58420145160629_kernel<<<dim3(B / 64), dim3(THREADS), 0, stream>>>(x, cp, out);
}